// Round 4
// baseline (71.990 us; speedup 1.0000x reference)
//
#include <hip/hip_runtime.h>
#include <stdint.h>

#define TT 256
#define BB 2048
#define AA 18
#define NTB (TT * BB)
#define NSEG 128
#define SEGLEN 2     // TT / NSEG
#define NWAVE (NSEG * (BB / 64))   // 4096 waves
#define NBLK (NWAVE / 4)           // 1024 blocks of 256 threads

// ws layout:
//   [0..31]   4 doubles: acc[0]=S_ent, acc[1]=S_pol, acc[2]=S_val, acc[3]=spare
//   [32..35]  int flag: 1 = done is 1-byte elements, 0 = 4-byte elements
//   [40..43]  int counter: fold_k last-block detection
//   [64..)    5 float arrays [NSEG*BB]: A, Bv, sv1, sv2, sp1  (5.2 MB)

#define ARR_ELEMS (NSEG * BB)

__global__ __launch_bounds__(256) void init_k(const int* __restrict__ done_w,
                                              double* __restrict__ acc,
                                              int* __restrict__ flag,
                                              int* __restrict__ counter) {
    int tid = threadIdx.x;
    if (tid < 4) acc[tid] = 0.0;
    if (tid == 0) { *flag = 0; *counter = 0; }
    __syncthreads();
    int bad = 0;
    for (int i = tid; i < 1024; i += 256) {
        int v = done_w[i];
        if (!(v == 0 || v == 1 || v == 0x3F800000)) bad = 1;
    }
    if (bad) atomicOr(flag, 1);
}

// One fused pass: entropy + gather + per-segment scan summaries.
// Wave u (0..4095): segment s = u>>5 (timesteps [s*2, s*2+2)), col-group
// g = u&31 (columns g*64+lane).
__global__ __launch_bounds__(256) void fused_k(
    const float* __restrict__ policy,
    const float* __restrict__ behavior,
    const float* __restrict__ rewards,
    const float* __restrict__ values,
    const float* __restrict__ next_values,
    const int* __restrict__ actions,
    const void* __restrict__ done,
    const int* __restrict__ flag,
    float* __restrict__ wsf,     // 5 arrays of ARR_ELEMS
    double* __restrict__ acc)
{
    int lane = threadIdx.x & 63;
    int w = threadIdx.x >> 6;
    int u = blockIdx.x * 4 + w;
    int s = u >> 5;
    int g = u & 31;
    int b = g * 64 + lane;
    int t_hi = s * SEGLEN + SEGLEN - 1;

    bool bytelay = (*flag != 0);
    const uint8_t* d8 = (const uint8_t*)done;
    const int* d32 = (const int*)done;

    float ent = 0.f;
    float vacc = 0.f, P = 1.f;
    float sv0 = 0.f, sv1 = 0.f, sv2 = 0.f;
    float sp0 = 0.f, sp1 = 0.f;

#pragma unroll
    for (int i = 0; i < SEGLEN; ++i) {
        int t = t_hi - i;
        int r = t * BB + b;

        // --- policy row: entropy + select pi, log(pi) ---
        int a = actions[r];
        const float* prow = policy + (size_t)r * AA;
        float pi = 1.f, lpi = 0.f;
#pragma unroll
        for (int j = 0; j < 9; ++j) {
            float2 v = *(const float2*)(prow + 2 * j);
            float l0 = __logf(v.x + 1e-10f);
            float l1 = __logf(v.y + 1e-10f);
            ent = fmaf(v.x, l0, ent);
            ent = fmaf(v.y, l1, ent);
            if (2 * j == a)     { pi = v.x; lpi = l0; }
            if (2 * j + 1 == a) { pi = v.y; lpi = l1; }
        }
        float mu = behavior[(size_t)r * AA + a];
        float c = fminf(1.0f, pi / mu);

        // --- scan inputs ---
        float rw = rewards[r];
        float v0 = values[r];
        float nv = next_values[r];
        int dn = bytelay ? (int)d8[r] : d32[r];
        float disc = dn ? 0.f : 0.99f;
        const float* vt1p = (t == TT - 1) ? (next_values + r) : (values + r + BB);
        float vt1 = *vt1p;

        float cr = fminf(1.f, fmaxf(-1.f, rw));
        float base = cr - v0;
        float dlt = c * fmaf(disc, vt1, base);
        float gg = disc * c;

        vacc = fmaf(gg, vacc, dlt);          // local vs_minus_v (carry = 0)
        P *= gg;                             // P[t] = prod_{tau=t..t_hi} g
        sv0 = fmaf(vacc, vacc, sv0);
        sv1 = fmaf(P, vacc, sv1);
        sv2 = fmaf(P, P, sv2);

        float adv = c * fmaf(disc, nv, base);      // pg_adv_vt
        float q = fmaf(disc, v0, base);            // cr + disc*v0 - v0
        float al = adv * lpi;
        sp0 = fmaf(al, fmaf(disc, vacc, q), sp0);  // carry-independent part
        sp1 = fmaf(al * disc, P, sp1);             // coefficient of carry
    }

    // per-(segment, column) summaries for the fold kernel
    int idx = s * BB + b;
    wsf[0 * ARR_ELEMS + idx] = P;      // A
    wsf[1 * ARR_ELEMS + idx] = vacc;   // Bv (local value at segment bottom)
    wsf[2 * ARR_ELEMS + idx] = sv1;
    wsf[3 * ARR_ELEMS + idx] = sv2;
    wsf[4 * ARR_ELEMS + idx] = sp1;

    // block-reduce carry-independent sums
    for (int off = 32; off > 0; off >>= 1) {
        ent += __shfl_down(ent, off);
        sv0 += __shfl_down(sv0, off);
        sp0 += __shfl_down(sp0, off);
    }
    __shared__ float se[4], sv[4], sp[4];
    if (lane == 0) { se[w] = ent; sv[w] = sv0; sp[w] = sp0; }
    __syncthreads();
    if (threadIdx.x == 0) {
        atomicAdd(&acc[0], (double)(se[0] + se[1] + se[2] + se[3]));
        atomicAdd(&acc[2], (double)(sv[0] + sv[1] + sv[2] + sv[3]));
        atomicAdd(&acc[1], (double)(sp[0] + sp[1] + sp[2] + sp[3]));
    }
}

// Fold segment carries per column; add carry-coupling corrections.
// Last block finishes the loss and writes d_out (merged final_k).
__global__ __launch_bounds__(256) void fold_k(
    const float* __restrict__ wsf,
    double* __restrict__ acc,
    int* __restrict__ counter,
    float* __restrict__ out)
{
    int b = blockIdx.x * 256 + threadIdx.x;   // 0..2047
    float C = 0.f;                            // vacc at segment top
    float svadd = 0.f, spadd = 0.f;
#pragma unroll 8
    for (int s = NSEG - 1; s >= 0; --s) {
        int idx = s * BB + b;
        float A   = wsf[0 * ARR_ELEMS + idx];
        float Bv  = wsf[1 * ARR_ELEMS + idx];
        float sv1 = wsf[2 * ARR_ELEMS + idx];
        float sv2 = wsf[3 * ARR_ELEMS + idx];
        float sp1 = wsf[4 * ARR_ELEMS + idx];
        // sum over segment: (vloc + P*C)^2 = vloc^2 + 2C*P*vloc + C^2*P^2
        svadd = fmaf(2.f * C, sv1, svadd);
        svadd = fmaf(C * C, sv2, svadd);
        spadd = fmaf(C, sp1, spadd);
        C = fmaf(A, C, Bv);                   // carry for segment below
    }
    for (int off = 32; off > 0; off >>= 1) {
        svadd += __shfl_down(svadd, off);
        spadd += __shfl_down(spadd, off);
    }
    __shared__ float s1[4], s2[4];
    int lane = threadIdx.x & 63, w = threadIdx.x >> 6;
    if (lane == 0) { s1[w] = svadd; s2[w] = spadd; }
    __syncthreads();
    if (threadIdx.x == 0) {
        atomicAdd(&acc[2], (double)(s1[0] + s1[1] + s1[2] + s1[3]));
        atomicAdd(&acc[1], (double)(s2[0] + s2[1] + s2[2] + s2[3]));
        __threadfence();
        int prev = atomicAdd(counter, 1);
        if (prev == gridDim.x - 1) {
            // coherent read of final acc values (dodge stale L2 across XCDs)
            double e = atomicAdd(&acc[0], 0.0);
            double p = atomicAdd(&acc[1], 0.0);
            double v = atomicAdd(&acc[2], 0.0);
            // loss = (S_val - S_pol - 0.01*S_ent) / NTB
            *out = (float)((v - p - 0.01 * e) / (double)NTB);
        }
    }
}

extern "C" void kernel_launch(void* const* d_in, const int* in_sizes, int n_in,
                              void* d_out, int out_size, void* d_ws, size_t ws_size,
                              hipStream_t stream) {
    const float* policy      = (const float*)d_in[0];
    const float* behavior    = (const float*)d_in[1];
    const float* rewards     = (const float*)d_in[2];
    const float* values      = (const float*)d_in[3];
    const float* next_values = (const float*)d_in[4];
    const int*   actions     = (const int*)d_in[5];
    const void*  done        = d_in[6];

    double* acc     = (double*)d_ws;
    int*    flag    = (int*)((char*)d_ws + 32);
    int*    counter = (int*)((char*)d_ws + 40);
    float*  wsf     = (float*)((char*)d_ws + 64);

    init_k<<<1, 256, 0, stream>>>((const int*)done, acc, flag, counter);
    fused_k<<<NBLK, 256, 0, stream>>>(policy, behavior, rewards, values,
                                      next_values, actions, done, flag,
                                      wsf, acc);
    fold_k<<<BB / 256, 256, 0, stream>>>(wsf, acc, counter, (float*)d_out);
}

// Round 5
// 70.864 us; speedup vs baseline: 1.0159x; 1.0159x over previous
//
#include <hip/hip_runtime.h>
#include <stdint.h>

#define TT 256
#define BB 2048
#define AA 18
#define NTB (TT * BB)
#define NSEG 128
#define SEGLEN 2     // TT / NSEG
#define NWAVE (NSEG * (BB / 64))   // 4096 waves
#define NBLK (NWAVE / 4)           // 1024 blocks of 256 threads
#define LDST 65                    // LDS row stride (floats), bank-conflict-free

// ws layout:
//   [0..31]   4 doubles: acc[0]=S_ent, acc[1]=S_pol, acc[2]=S_val, acc[3]=spare
//   [32..35]  int flag: 1 = done is 1-byte elements, 0 = 4-byte elements
//   [40..43]  int counter: fold_k last-block detection
//   [64..)    5 float arrays [NSEG*BB]: A, Bv, sv1, sv2, sp1  (5.2 MB)

#define ARR_ELEMS (NSEG * BB)

__global__ __launch_bounds__(256) void init_k(const int* __restrict__ done_w,
                                              double* __restrict__ acc,
                                              int* __restrict__ flag,
                                              int* __restrict__ counter) {
    int tid = threadIdx.x;
    if (tid < 4) acc[tid] = 0.0;
    if (tid == 0) { *flag = 0; *counter = 0; }
    __syncthreads();
    int bad = 0;
    for (int i = tid; i < 1024; i += 256) {
        int v = done_w[i];
        if (!(v == 0 || v == 1 || v == 0x3F800000)) bad = 1;
    }
    if (bad) atomicOr(flag, 1);
}

// Fused pass: coalesced policy staging via LDS + entropy + gather +
// per-segment scan summaries. Wave u: segment s = u>>5 (timesteps
// [s*2, s*2+2)), col-group g = u&31 (columns g*64+lane). Each lane owns one
// column; the wave's 64 lanes are 64 CONSECUTIVE policy rows at fixed t, so
// staging is 9 fully-coalesced float2 loads per lane.
__global__ __launch_bounds__(256) void fused_k(
    const float* __restrict__ policy,
    const float* __restrict__ behavior,
    const float* __restrict__ rewards,
    const float* __restrict__ values,
    const float* __restrict__ next_values,
    const int* __restrict__ actions,
    const void* __restrict__ done,
    const int* __restrict__ flag,
    float* __restrict__ wsf,     // 5 arrays of ARR_ELEMS
    double* __restrict__ acc)
{
    int lane = threadIdx.x & 63;
    int w = threadIdx.x >> 6;
    int u = blockIdx.x * 4 + w;
    int s = u >> 5;
    int g = u & 31;
    int b = g * 64 + lane;
    int t_hi = s * SEGLEN + SEGLEN - 1;

    bool bytelay = (*flag != 0);
    const uint8_t* d8 = (const uint8_t*)done;
    const int* d32 = (const int*)done;

    // transposed staging: L[e*LDST + row], row = lane. 18*65*4 = 4680 B/wave.
    __shared__ float lpol[4][AA * LDST];
    float* L = lpol[w];

    float ent = 0.f;
    float vacc = 0.f, P = 1.f;
    float sv0 = 0.f, sv1 = 0.f, sv2 = 0.f;
    float sp0 = 0.f, sp1 = 0.f;

#pragma unroll
    for (int i = 0; i < SEGLEN; ++i) {
        int t = t_hi - i;
        int r = t * BB + b;
        int rbase = t * BB + g * 64;   // first row this wave stages

        // --- coalesced stage: 64 rows x 18 floats = 576 float2 ---
        const float* gsrc = policy + (size_t)rbase * AA;
#pragma unroll
        for (int k = 0; k < 9; ++k) {
            int m = lane + 64 * k;             // float2 index 0..575
            float2 v = *(const float2*)(gsrc + 2 * m);
            int row = m / 9;
            int h = m - row * 9;               // floats 2h, 2h+1 of row
            L[(2 * h) * LDST + row]     = v.x;
            L[(2 * h + 1) * LDST + row] = v.y;
        }
        __syncthreads();

        // --- per-row compute from LDS ---
        int a = actions[r];
        float pi = 1.f, lpi = 0.f;
#pragma unroll
        for (int e = 0; e < AA; ++e) {
            float pe = L[e * LDST + lane];
            float le = __logf(pe + 1e-10f);
            ent = fmaf(pe, le, ent);
            if (e == a) { pi = pe; lpi = le; }
        }
        __syncthreads();

        float mu = behavior[(size_t)r * AA + a];   // the one scattered load
        float c = fminf(1.0f, pi / mu);

        float rw = rewards[r];
        float v0 = values[r];
        float nv = next_values[r];
        int dn = bytelay ? (int)d8[r] : d32[r];
        float disc = dn ? 0.f : 0.99f;
        float vt1 = (t == TT - 1) ? nv : values[r + BB];

        float cr = fminf(1.f, fmaxf(-1.f, rw));
        float base = cr - v0;
        float dlt = c * fmaf(disc, vt1, base);
        float gg = disc * c;

        vacc = fmaf(gg, vacc, dlt);          // local vs_minus_v (carry = 0)
        P *= gg;                             // P[t] = prod g over segment
        sv0 = fmaf(vacc, vacc, sv0);
        sv1 = fmaf(P, vacc, sv1);
        sv2 = fmaf(P, P, sv2);

        float adv = c * fmaf(disc, nv, base);      // pg_adv_vt
        float q = fmaf(disc, v0, base);            // cr + disc*v0 - v0
        float al = adv * lpi;
        sp0 = fmaf(al, fmaf(disc, vacc, q), sp0);  // carry-independent part
        sp1 = fmaf(al * disc, P, sp1);             // coefficient of carry
    }

    // per-(segment, column) summaries
    int idx = s * BB + b;
    wsf[0 * ARR_ELEMS + idx] = P;
    wsf[1 * ARR_ELEMS + idx] = vacc;
    wsf[2 * ARR_ELEMS + idx] = sv1;
    wsf[3 * ARR_ELEMS + idx] = sv2;
    wsf[4 * ARR_ELEMS + idx] = sp1;

    // block-reduce carry-independent sums
    for (int off = 32; off > 0; off >>= 1) {
        ent += __shfl_down(ent, off);
        sv0 += __shfl_down(sv0, off);
        sp0 += __shfl_down(sp0, off);
    }
    __shared__ float se[4], sv[4], sp[4];
    if (lane == 0) { se[w] = ent; sv[w] = sv0; sp[w] = sp0; }
    __syncthreads();
    if (threadIdx.x == 0) {
        atomicAdd(&acc[0], (double)(se[0] + se[1] + se[2] + se[3]));
        atomicAdd(&acc[2], (double)(sv[0] + sv[1] + sv[2] + sv[3]));
        atomicAdd(&acc[1], (double)(sp[0] + sp[1] + sp[2] + sp[3]));
    }
}

// Fold segment carries per column; add carry-coupling corrections.
// 32 blocks x 64 threads (one wave each), thread = one column.
__global__ __launch_bounds__(64) void fold_k(
    const float* __restrict__ wsf,
    double* __restrict__ acc,
    int* __restrict__ counter,
    float* __restrict__ out)
{
    int b = blockIdx.x * 64 + threadIdx.x;    // 0..2047
    float C = 0.f;                            // vacc at segment top
    float svadd = 0.f, spadd = 0.f;
#pragma unroll 8
    for (int s = NSEG - 1; s >= 0; --s) {
        int idx = s * BB + b;
        float A   = wsf[0 * ARR_ELEMS + idx];
        float Bv  = wsf[1 * ARR_ELEMS + idx];
        float sv1 = wsf[2 * ARR_ELEMS + idx];
        float sv2 = wsf[3 * ARR_ELEMS + idx];
        float sp1 = wsf[4 * ARR_ELEMS + idx];
        // segment sum: (vloc + P*C)^2 = vloc^2 + 2C*P*vloc + C^2*P^2
        svadd = fmaf(2.f * C, sv1, svadd);
        svadd = fmaf(C * C, sv2, svadd);
        spadd = fmaf(C, sp1, spadd);
        C = fmaf(A, C, Bv);                   // carry for segment below
    }
    for (int off = 32; off > 0; off >>= 1) {
        svadd += __shfl_down(svadd, off);
        spadd += __shfl_down(spadd, off);
    }
    if (threadIdx.x == 0) {
        atomicAdd(&acc[2], (double)svadd);
        atomicAdd(&acc[1], (double)spadd);
        __threadfence();
        int prev = atomicAdd(counter, 1);
        if (prev == gridDim.x - 1) {
            double e = atomicAdd(&acc[0], 0.0);
            double p = atomicAdd(&acc[1], 0.0);
            double v = atomicAdd(&acc[2], 0.0);
            // loss = (S_val - S_pol - 0.01*S_ent) / NTB
            *out = (float)((v - p - 0.01 * e) / (double)NTB);
        }
    }
}

extern "C" void kernel_launch(void* const* d_in, const int* in_sizes, int n_in,
                              void* d_out, int out_size, void* d_ws, size_t ws_size,
                              hipStream_t stream) {
    const float* policy      = (const float*)d_in[0];
    const float* behavior    = (const float*)d_in[1];
    const float* rewards     = (const float*)d_in[2];
    const float* values      = (const float*)d_in[3];
    const float* next_values = (const float*)d_in[4];
    const int*   actions     = (const int*)d_in[5];
    const void*  done        = d_in[6];

    double* acc     = (double*)d_ws;
    int*    flag    = (int*)((char*)d_ws + 32);
    int*    counter = (int*)((char*)d_ws + 40);
    float*  wsf     = (float*)((char*)d_ws + 64);

    init_k<<<1, 256, 0, stream>>>((const int*)done, acc, flag, counter);
    fused_k<<<NBLK, 256, 0, stream>>>(policy, behavior, rewards, values,
                                      next_values, actions, done, flag,
                                      wsf, acc);
    fold_k<<<32, 64, 0, stream>>>(wsf, acc, counter, (float*)d_out);
}

// Round 6
// 39.153 us; speedup vs baseline: 1.8387x; 1.8099x over previous
//
#include <hip/hip_runtime.h>
#include <stdint.h>

#define TT 256
#define BB 2048
#define AA 18
#define NTB (TT * BB)
#define NSEG 128
#define SEGLEN 2     // TT / NSEG
#define NWAVE (NSEG * (BB / 64))   // 4096 waves
#define NBLK (NWAVE / 4)           // 1024 blocks of 256 threads
#define LDST 65                    // LDS row stride (floats), conflict-free

// ws layout (floats unless noted):
//   [0]        int flag: 1 = done is 1-byte elements, 0 = 4-byte
//   [64..)     pben[NBLK], psv[NBLK], psp[NBLK]      (per-block partials)
//   then       fsv[32], fsp[32]                      (fold partials)
//   then       wsf: 5 arrays of NSEG*BB              (segment summaries, 5.2 MB)

#define ARR_ELEMS (NSEG * BB)

__global__ __launch_bounds__(256) void init_k(const int* __restrict__ done_w,
                                              int* __restrict__ flag) {
    int tid = threadIdx.x;
    if (tid == 0) *flag = 0;
    __syncthreads();
    int bad = 0;
    for (int i = tid; i < 1024; i += 256) {
        int v = done_w[i];
        if (!(v == 0 || v == 1 || v == 0x3F800000)) bad = 1;
    }
    if (bad) atomicOr(flag, 1);
}

// Fused pass: coalesced policy staging via LDS + entropy + gather +
// per-segment scan summaries. NO same-address atomics: per-block partials
// are stored to distinct slots.
__global__ __launch_bounds__(256) void fused_k(
    const float* __restrict__ policy,
    const float* __restrict__ behavior,
    const float* __restrict__ rewards,
    const float* __restrict__ values,
    const float* __restrict__ next_values,
    const int* __restrict__ actions,
    const void* __restrict__ done,
    const int* __restrict__ flag,
    float* __restrict__ wsf,      // 5 arrays of ARR_ELEMS
    float* __restrict__ pben,     // [NBLK]
    float* __restrict__ psv,      // [NBLK]
    float* __restrict__ psp)      // [NBLK]
{
    int lane = threadIdx.x & 63;
    int w = threadIdx.x >> 6;
    int u = blockIdx.x * 4 + w;
    int s = u >> 5;
    int g = u & 31;
    int b = g * 64 + lane;
    int t_hi = s * SEGLEN + SEGLEN - 1;

    bool bytelay = (*flag != 0);
    const uint8_t* d8 = (const uint8_t*)done;
    const int* d32 = (const int*)done;

    __shared__ float lpol[4][AA * LDST];
    float* L = lpol[w];

    float ent = 0.f;
    float vacc = 0.f, P = 1.f;
    float sv0 = 0.f, sv1 = 0.f, sv2 = 0.f;
    float sp0 = 0.f, sp1 = 0.f;

#pragma unroll
    for (int i = 0; i < SEGLEN; ++i) {
        int t = t_hi - i;
        int r = t * BB + b;
        int rbase = t * BB + g * 64;

        // coalesced stage: 64 rows x 18 floats = 576 float2
        const float* gsrc = policy + (size_t)rbase * AA;
#pragma unroll
        for (int k = 0; k < 9; ++k) {
            int m = lane + 64 * k;
            float2 v = *(const float2*)(gsrc + 2 * m);
            int row = m / 9;
            int h = m - row * 9;
            L[(2 * h) * LDST + row]     = v.x;
            L[(2 * h + 1) * LDST + row] = v.y;
        }
        __syncthreads();

        int a = actions[r];
        float pi = 1.f, lpi = 0.f;
#pragma unroll
        for (int e = 0; e < AA; ++e) {
            float pe = L[e * LDST + lane];
            float le = __logf(pe + 1e-10f);
            ent = fmaf(pe, le, ent);
            if (e == a) { pi = pe; lpi = le; }
        }
        __syncthreads();

        float mu = behavior[(size_t)r * AA + a];
        float c = fminf(1.0f, pi / mu);

        float rw = rewards[r];
        float v0 = values[r];
        float nv = next_values[r];
        int dn = bytelay ? (int)d8[r] : d32[r];
        float disc = dn ? 0.f : 0.99f;
        float vt1 = (t == TT - 1) ? nv : values[r + BB];

        float cr = fminf(1.f, fmaxf(-1.f, rw));
        float base = cr - v0;
        float dlt = c * fmaf(disc, vt1, base);
        float gg = disc * c;

        vacc = fmaf(gg, vacc, dlt);
        P *= gg;
        sv0 = fmaf(vacc, vacc, sv0);
        sv1 = fmaf(P, vacc, sv1);
        sv2 = fmaf(P, P, sv2);

        float adv = c * fmaf(disc, nv, base);
        float q = fmaf(disc, v0, base);
        float al = adv * lpi;
        sp0 = fmaf(al, fmaf(disc, vacc, q), sp0);
        sp1 = fmaf(al * disc, P, sp1);
    }

    int idx = s * BB + b;
    wsf[0 * ARR_ELEMS + idx] = P;
    wsf[1 * ARR_ELEMS + idx] = vacc;
    wsf[2 * ARR_ELEMS + idx] = sv1;
    wsf[3 * ARR_ELEMS + idx] = sv2;
    wsf[4 * ARR_ELEMS + idx] = sp1;

    for (int off = 32; off > 0; off >>= 1) {
        ent += __shfl_down(ent, off);
        sv0 += __shfl_down(sv0, off);
        sp0 += __shfl_down(sp0, off);
    }
    __shared__ float se[4], sv[4], sp[4];
    if (lane == 0) { se[w] = ent; sv[w] = sv0; sp[w] = sp0; }
    __syncthreads();
    if (threadIdx.x == 0) {
        pben[blockIdx.x] = se[0] + se[1] + se[2] + se[3];
        psv[blockIdx.x]  = sv[0] + sv[1] + sv[2] + sv[3];
        psp[blockIdx.x]  = sp[0] + sp[1] + sp[2] + sp[3];
    }
}

// Fold segment carries per column; store per-block partials (no contention).
__global__ __launch_bounds__(64) void fold_k(
    const float* __restrict__ wsf,
    float* __restrict__ fsv,     // [32]
    float* __restrict__ fsp)     // [32]
{
    int b = blockIdx.x * 64 + threadIdx.x;    // 0..2047
    float C = 0.f;
    float svadd = 0.f, spadd = 0.f;
#pragma unroll 8
    for (int s = NSEG - 1; s >= 0; --s) {
        int idx = s * BB + b;
        float A   = wsf[0 * ARR_ELEMS + idx];
        float Bv  = wsf[1 * ARR_ELEMS + idx];
        float sv1 = wsf[2 * ARR_ELEMS + idx];
        float sv2 = wsf[3 * ARR_ELEMS + idx];
        float sp1 = wsf[4 * ARR_ELEMS + idx];
        svadd = fmaf(2.f * C, sv1, svadd);
        svadd = fmaf(C * C, sv2, svadd);
        spadd = fmaf(C, sp1, spadd);
        C = fmaf(A, C, Bv);
    }
    for (int off = 32; off > 0; off >>= 1) {
        svadd += __shfl_down(svadd, off);
        spadd += __shfl_down(spadd, off);
    }
    if (threadIdx.x == 0) {
        fsv[blockIdx.x] = svadd;
        fsp[blockIdx.x] = spadd;
    }
}

// Single-block final reduce: 1024x3 + 32x2 floats -> loss.
__global__ __launch_bounds__(256) void final_k(
    const float* __restrict__ pben,
    const float* __restrict__ psv,
    const float* __restrict__ psp,
    const float* __restrict__ fsv,
    const float* __restrict__ fsp,
    float* __restrict__ out)
{
    int tid = threadIdx.x;
    float e = 0.f, v = 0.f, p = 0.f;
#pragma unroll
    for (int i = 0; i < NBLK / 256; ++i) {
        int j = tid + 256 * i;
        e += pben[j];
        v += psv[j];
        p += psp[j];
    }
    if (tid < 32) { v += fsv[tid]; p += fsp[tid]; }
    for (int off = 32; off > 0; off >>= 1) {
        e += __shfl_down(e, off);
        v += __shfl_down(v, off);
        p += __shfl_down(p, off);
    }
    __shared__ float s0[4], s1[4], s2[4];
    int lane = tid & 63, w = tid >> 6;
    if (lane == 0) { s0[w] = e; s1[w] = v; s2[w] = p; }
    __syncthreads();
    if (tid == 0) {
        double E = (double)s0[0] + s0[1] + s0[2] + s0[3];
        double V = (double)s1[0] + s1[1] + s1[2] + s1[3];
        double Pp = (double)s2[0] + s2[1] + s2[2] + s2[3];
        // loss = (S_val - S_pol - 0.01*S_ent) / NTB
        out[0] = (float)((V - Pp - 0.01 * E) / (double)NTB);
    }
}

extern "C" void kernel_launch(void* const* d_in, const int* in_sizes, int n_in,
                              void* d_out, int out_size, void* d_ws, size_t ws_size,
                              hipStream_t stream) {
    const float* policy      = (const float*)d_in[0];
    const float* behavior    = (const float*)d_in[1];
    const float* rewards     = (const float*)d_in[2];
    const float* values      = (const float*)d_in[3];
    const float* next_values = (const float*)d_in[4];
    const int*   actions     = (const int*)d_in[5];
    const void*  done        = d_in[6];

    int*   flag = (int*)d_ws;
    float* base = (float*)((char*)d_ws + 64);
    float* pben = base;                 // NBLK
    float* psv  = pben + NBLK;          // NBLK
    float* psp  = psv + NBLK;           // NBLK
    float* fsv  = psp + NBLK;           // 32
    float* fsp  = fsv + 32;             // 32
    float* wsf  = fsp + 32;             // 5 * ARR_ELEMS

    init_k<<<1, 256, 0, stream>>>((const int*)done, flag);
    fused_k<<<NBLK, 256, 0, stream>>>(policy, behavior, rewards, values,
                                      next_values, actions, done, flag,
                                      wsf, pben, psv, psp);
    fold_k<<<32, 64, 0, stream>>>(wsf, fsv, fsp);
    final_k<<<1, 256, 0, stream>>>(pben, psv, psp, fsv, fsp, (float*)d_out);
}

// Round 7
// 35.354 us; speedup vs baseline: 2.0362x; 1.1074x over previous
//
#include <hip/hip_runtime.h>
#include <stdint.h>

#define TT 256
#define BB 2048
#define AA 18
#define NTB (TT * BB)
#define TBLK 8        // time-blocks (8 x 32 timesteps)
#define TPB 32        // timesteps per block
#define WPB 16        // waves per block
#define SEGLEN 2      // timesteps per wave
#define NBLK 256      // TBLK * 32 col-groups
#define LDST 65       // LDS row stride (floats), conflict-free
#define LN2 0.69314718055994531f

// ws layout:
//   [0..3]               int counter (zeroed by hipMemsetAsync each call)
//   [128 ..)             part[NBLK*32] floats: per-block 128B line {ent, sv0, sp0}
//   [128+NBLK*128 ..)    wsf[5][TBLK][BB] composed tuples (320 KB)

__global__ __launch_bounds__(1024) void fused_k(
    const float* __restrict__ policy,
    const float* __restrict__ behavior,
    const float* __restrict__ rewards,
    const float* __restrict__ values,
    const float* __restrict__ next_values,
    const int* __restrict__ actions,
    const void* __restrict__ done,
    float* __restrict__ part,
    float* __restrict__ wsf,
    int* __restrict__ counter,
    float* __restrict__ out)
{
    int tid = threadIdx.x;
    int lane = tid & 63;
    int w = tid >> 6;                 // wave 0..15
    int bid = blockIdx.x;
    int tb = bid >> 5;                // time-block 0..7
    int g = bid & 31;                 // col-group 0..31

    __shared__ float lpol[WPB][AA * LDST];   // 74.9 KB, wave-private tiles
    __shared__ float tup[WPB][5][64];        // 20.5 KB wave tuples
    __shared__ float red[WPB][3];
    __shared__ int sflag[WPB];
    __shared__ int is_last;

    // --- done-layout detection: every block scans first 4KB as ints ---
    {
        const int* di = (const int*)done;
        int v = di[tid];
        int bad = !(v == 0 || v == 1 || v == 0x3F800000);
        bad = __any(bad);
        if (lane == 0) sflag[w] = bad;
    }
    __syncthreads();
    int anybad = 0;
#pragma unroll
    for (int i = 0; i < WPB; ++i) anybad |= sflag[i];
    bool bytelay = (anybad != 0);
    const uint8_t* d8 = (const uint8_t*)done;
    const int* d32 = (const int*)done;

    float* L = lpol[w];
    int b = g * 64 + lane;
    int t_hi = tb * TPB + w * SEGLEN + (SEGLEN - 1);

    float ent2 = 0.f;
    float vacc = 0.f, P = 1.f;
    float sv0 = 0.f, sv1 = 0.f, sv2 = 0.f;
    float sp0 = 0.f, sp1 = 0.f;

#pragma unroll
    for (int i = 0; i < SEGLEN; ++i) {
        int t = t_hi - i;
        int r = t * BB + b;
        int rbase = t * BB + g * 64;

        // coalesced stage into wave-private LDS tile (no barrier needed)
        const float* gsrc = policy + (size_t)rbase * AA;
#pragma unroll
        for (int k = 0; k < 9; ++k) {
            int m = lane + 64 * k;
            float2 v = *(const float2*)(gsrc + 2 * m);
            int row = m / 9;
            int h = m - row * 9;
            L[(2 * h) * LDST + row]     = v.x;
            L[(2 * h + 1) * LDST + row] = v.y;
        }

        int a = actions[r];
        float pi = 1.f, l2pi = 0.f;
#pragma unroll
        for (int e = 0; e < AA; ++e) {
            float pe = L[e * LDST + lane];
            float le = __log2f(pe + 1e-10f);
            ent2 = fmaf(pe, le, ent2);
            if (e == a) { pi = pe; l2pi = le; }
        }
        float lpi = LN2 * l2pi;
        float mu = behavior[(size_t)r * AA + a];
        float c = fminf(1.0f, pi / mu);

        float rw = rewards[r];
        float v0 = values[r];
        float nv = next_values[r];
        int dn = bytelay ? (int)d8[r] : d32[r];
        float disc = dn ? 0.f : 0.99f;
        float vt1 = (t == TT - 1) ? nv : values[r + BB];

        float cr = fminf(1.f, fmaxf(-1.f, rw));
        float base = cr - v0;
        float dlt = c * fmaf(disc, vt1, base);
        float gg = disc * c;

        vacc = fmaf(gg, vacc, dlt);          // local value (zero carry)
        P *= gg;                             // carry coefficient
        sv0 = fmaf(vacc, vacc, sv0);
        sv1 = fmaf(P, vacc, sv1);
        sv2 = fmaf(P, P, sv2);

        float adv = c * fmaf(disc, nv, base);
        float q = fmaf(disc, v0, base);
        float al = adv * lpi;
        sp0 = fmaf(al, fmaf(disc, vacc, q), sp0);
        sp1 = fmaf(al * disc, P, sp1);
    }

    // stash wave tuple + wave-reduced carry-independent sums
    tup[w][0][lane] = P;
    tup[w][1][lane] = vacc;
    tup[w][2][lane] = sv1;
    tup[w][3][lane] = sv2;
    tup[w][4][lane] = sp1;

    float ent = LN2 * ent2;
    for (int off = 32; off > 0; off >>= 1) {
        ent += __shfl_down(ent, off);
        sv0 += __shfl_down(sv0, off);
        sp0 += __shfl_down(sp0, off);
    }
    if (lane == 0) { red[w][0] = ent; red[w][1] = sv0; red[w][2] = sp0; }
    __syncthreads();

    if (w == 0) {
        // compose 16 wave tuples (descending: wave 15 = latest timesteps)
        float A  = tup[15][0][lane];
        float Bv = tup[15][1][lane];
        float s1 = tup[15][2][lane];
        float s2 = tup[15][3][lane];
        float p1 = tup[15][4][lane];
        float svx = 0.f, spx = 0.f;
#pragma unroll
        for (int s = WPB - 2; s >= 0; --s) {
            float Al  = tup[s][0][lane];
            float Bl  = tup[s][1][lane];
            float s1l = tup[s][2][lane];
            float s2l = tup[s][3][lane];
            float p1l = tup[s][4][lane];
            svx = fmaf(2.f * Bv, s1l, svx);
            svx = fmaf(Bv * Bv, s2l, svx);
            spx = fmaf(Bv, p1l, spx);
            s1 = fmaf(A, fmaf(Bv, s2l, s1l), s1);
            s2 = fmaf(A * A, s2l, s2);
            p1 = fmaf(A, p1l, p1);
            Bv = fmaf(Al, Bv, Bl);
            A  = A * Al;
        }
        int col = g * 64 + lane;
        wsf[(0 * TBLK + tb) * BB + col] = A;
        wsf[(1 * TBLK + tb) * BB + col] = Bv;
        wsf[(2 * TBLK + tb) * BB + col] = s1;
        wsf[(3 * TBLK + tb) * BB + col] = s2;
        wsf[(4 * TBLK + tb) * BB + col] = p1;

        // reduce composition extras across 64 lanes
        for (int off = 32; off > 0; off >>= 1) {
            svx += __shfl_down(svx, off);
            spx += __shfl_down(spx, off);
        }
        // gather per-wave reductions (lanes 0..15)
        float eT = 0.f, vT = 0.f, pT = 0.f;
        if (lane < WPB) { eT = red[lane][0]; vT = red[lane][1]; pT = red[lane][2]; }
        for (int off = 8; off > 0; off >>= 1) {
            eT += __shfl_down(eT, off);
            vT += __shfl_down(vT, off);
            pT += __shfl_down(pT, off);
        }
        if (lane == 0) {
            part[bid * 32 + 0] = eT;
            part[bid * 32 + 1] = vT + svx;
            part[bid * 32 + 2] = pT + spx;
            __threadfence();
            int prev = atomicAdd(counter, 1);
            is_last = (prev == NBLK - 1) ? 1 : 0;
        }
    }
    __syncthreads();
    if (!is_last) return;

    // ---- tail block: fold 8 composed tuples per column + final reduce ----
    float svT = 0.f, spT = 0.f;
#pragma unroll
    for (int cc = 0; cc < 2; ++cc) {
        int col = tid + cc * 1024;
        float C = 0.f;
#pragma unroll
        for (int t2 = TBLK - 1; t2 >= 0; --t2) {
            float A  = wsf[(0 * TBLK + t2) * BB + col];
            float Bv = wsf[(1 * TBLK + t2) * BB + col];
            float s1 = wsf[(2 * TBLK + t2) * BB + col];
            float s2 = wsf[(3 * TBLK + t2) * BB + col];
            float p1 = wsf[(4 * TBLK + t2) * BB + col];
            svT = fmaf(2.f * C, s1, svT);
            svT = fmaf(C * C, s2, svT);
            spT = fmaf(C, p1, spT);
            C = fmaf(A, C, Bv);
        }
    }
    float eT = 0.f, vT = svT, pT = spT;
    if (tid < NBLK) {
        eT  = part[tid * 32 + 0];
        vT += part[tid * 32 + 1];
        pT += part[tid * 32 + 2];
    }
    for (int off = 32; off > 0; off >>= 1) {
        eT += __shfl_down(eT, off);
        vT += __shfl_down(vT, off);
        pT += __shfl_down(pT, off);
    }
    __syncthreads();   // guard red reuse
    if (lane == 0) { red[w][0] = eT; red[w][1] = vT; red[w][2] = pT; }
    __syncthreads();
    if (tid == 0) {
        double E = 0.0, V = 0.0, Pp = 0.0;
#pragma unroll
        for (int i = 0; i < WPB; ++i) {
            E += red[i][0]; V += red[i][1]; Pp += red[i][2];
        }
        // loss = (S_val - S_pol - 0.01*S_ent) / NTB
        out[0] = (float)((V - Pp - 0.01 * E) / (double)NTB);
    }
}

extern "C" void kernel_launch(void* const* d_in, const int* in_sizes, int n_in,
                              void* d_out, int out_size, void* d_ws, size_t ws_size,
                              hipStream_t stream) {
    const float* policy      = (const float*)d_in[0];
    const float* behavior    = (const float*)d_in[1];
    const float* rewards     = (const float*)d_in[2];
    const float* values      = (const float*)d_in[3];
    const float* next_values = (const float*)d_in[4];
    const int*   actions     = (const int*)d_in[5];
    const void*  done        = d_in[6];

    int*   counter = (int*)d_ws;
    float* part    = (float*)((char*)d_ws + 128);
    float* wsf     = (float*)((char*)d_ws + 128 + NBLK * 32 * 4);

    hipMemsetAsync(counter, 0, 4, stream);
    fused_k<<<NBLK, 1024, 0, stream>>>(policy, behavior, rewards, values,
                                       next_values, actions, done,
                                       part, wsf, counter, (float*)d_out);
}